// Round 3
// baseline (3962.191 us; speedup 1.0000x reference)
//
#include <hip/hip_runtime.h>

#define EPS_BN 1e-4f

// ---------------------------------------------------------------------------
// bn_relu: out = relu((x - m) * (g * rsqrt(v+eps)) + b)
// bn layout: [4][C]. n_dev (if non-null) overrides n_const (device n1).
// ---------------------------------------------------------------------------
template <int C>
__global__ __launch_bounds__(256) void bn_relu_kernel(
    const float* __restrict__ x, const float* __restrict__ bn,
    float* __restrict__ out, int n_const, const int* __restrict__ n_dev)
{
    const int n = n_dev ? *n_dev : n_const;
    const long total = (long)n * C;
    const long i = (long)blockIdx.x * blockDim.x + threadIdx.x;
    if (i >= total) return;
    const int c = (int)(i & (C - 1));
    const float g = bn[c], b = bn[C + c], m = bn[2 * C + c], v = bn[3 * C + c];
    const float val = (x[i] - m) * (g * rsqrtf(v + EPS_BN)) + b;
    out[i] = fmaxf(val, 0.f);
}

// ---------------------------------------------------------------------------
// Build gather table: T[k*nb + pout[k,p]] = pin[k,p] for valid (non-pad) pairs.
// T pre-initialized to -1 (memset 0xFF). Each (out,k) slot hit at most once.
// ---------------------------------------------------------------------------
__global__ __launch_bounds__(256) void build_table_kernel(
    const int* __restrict__ pin, const int* __restrict__ pout,
    int K, int P, int pad_const, const int* __restrict__ pad_dev,
    int nb, int* __restrict__ T)
{
    const int e = blockIdx.x * 256 + threadIdx.x;
    if (e >= K * P) return;
    const int pad = pad_dev ? *pad_dev : pad_const;
    const int in = pin[e];
    if (in == pad) return;
    const int k = e / P;
    T[(size_t)k * nb + pout[e]] = in;
}

// ---------------------------------------------------------------------------
// Gather sparse conv: out[row] = sum_k x[T[k][row]] @ W[k]  (+ add[row])
// Thread = (row-group, cout); R consecutive rows per thread; W[k] in LDS.
// ix<0 branch is wave-uniform for COUT=64 (wave = one row-group).
// ---------------------------------------------------------------------------
template <int CIN, int COUT, int K, int R>
__global__ __launch_bounds__(256) void gconv_kernel(
    const float* __restrict__ x, const float* __restrict__ W,
    const int* __restrict__ T, int nb,
    const float* __restrict__ add, float* __restrict__ out,
    int n_const, const int* __restrict__ n_dev)
{
    __shared__ float Wl[CIN * COUT];
    const int n = n_dev ? *n_dev : n_const;
    constexpr int NRG = 256 / COUT;          // row-groups per block
    const int brow0 = blockIdx.x * (NRG * R);
    if (brow0 >= n) return;                  // uniform exit (before any sync)
    const int c = threadIdx.x % COUT;
    const int rg = threadIdx.x / COUT;
    const int row0 = brow0 + rg * R;

    float acc[R];
#pragma unroll
    for (int j = 0; j < R; ++j) acc[j] = 0.f;

    for (int k = 0; k < K; ++k) {
        __syncthreads();
        constexpr int NW = CIN * COUT / 4;
        const float4* Wg = (const float4*)(W + (size_t)k * CIN * COUT);
        for (int i = threadIdx.x; i < NW; i += 256) ((float4*)Wl)[i] = Wg[i];
        __syncthreads();

        int ix[R];
#pragma unroll
        for (int j = 0; j < R; ++j) {
            const int row = row0 + j;
            ix[j] = (row < n) ? T[(size_t)k * nb + row] : -1;
        }
#pragma unroll
        for (int q = 0; q < CIN / 4; ++q) {
            const float w0 = Wl[(4 * q + 0) * COUT + c];
            const float w1 = Wl[(4 * q + 1) * COUT + c];
            const float w2 = Wl[(4 * q + 2) * COUT + c];
            const float w3 = Wl[(4 * q + 3) * COUT + c];
#pragma unroll
            for (int j = 0; j < R; ++j) {
                if (ix[j] < 0) continue;
                const float4 xv = *(const float4*)(x + (size_t)ix[j] * CIN + 4 * q);
                acc[j] = fmaf(xv.x, w0, acc[j]);
                acc[j] = fmaf(xv.y, w1, acc[j]);
                acc[j] = fmaf(xv.z, w2, acc[j]);
                acc[j] = fmaf(xv.w, w3, acc[j]);
            }
        }
    }
#pragma unroll
    for (int j = 0; j < R; ++j) {
        const int row = row0 + j;
        if (row < n) {
            float v = acc[j];
            if (add) v += add[(size_t)row * COUT + c];
            out[(size_t)row * COUT + c] = v;
        }
    }
}

// ---------------------------------------------------------------------------
// concat: out[i][0:32] = a[i], out[i][32:64] = b[i]
// ---------------------------------------------------------------------------
__global__ __launch_bounds__(256) void concat_kernel(
    const float* __restrict__ a, const float* __restrict__ b,
    float* __restrict__ out, int n)
{
    const int i = blockIdx.x * 256 + threadIdx.x;
    if (i >= n * 64) return;
    const int row = i >> 6, c = i & 63;
    out[i] = (c < 32) ? a[row * 32 + c] : b[row * 32 + (c - 32)];
}

// ---------------------------------------------------------------------------
// dense matmul: out[n x 32] = x[n x 64] @ W[64 x 32]
// ---------------------------------------------------------------------------
__global__ __launch_bounds__(256) void dense_mm_kernel(
    const float* __restrict__ x, const float* __restrict__ W,
    float* __restrict__ out, int n)
{
    __shared__ float Wl[64 * 32];
    for (int i = threadIdx.x; i < 64 * 32; i += 256) Wl[i] = W[i];
    __syncthreads();
    const int idx = blockIdx.x * 256 + threadIdx.x;
    const int row = idx >> 5, c = idx & 31;
    if (row >= n) return;
    const float* xr = x + (size_t)row * 64;
    float acc = 0.f;
#pragma unroll
    for (int q = 0; q < 16; ++q) {
        const float4 xv = *(const float4*)(xr + 4 * q);
        acc = fmaf(xv.x, Wl[(4 * q + 0) * 32 + c], acc);
        acc = fmaf(xv.y, Wl[(4 * q + 1) * 32 + c], acc);
        acc = fmaf(xv.z, Wl[(4 * q + 2) * 32 + c], acc);
        acc = fmaf(xv.w, Wl[(4 * q + 3) * 32 + c], acc);
    }
    out[(size_t)row * 32 + c] = acc;
}

// ---------------------------------------------------------------------------

extern "C" void kernel_launch(void* const* d_in, const int* in_sizes, int n_in,
                              void* d_out, int out_size, void* d_ws, size_t ws_size,
                              hipStream_t stream)
{
    const float* feats   = (const float*)d_in[0];
    const float* res0_W  = (const float*)d_in[1];   // (2,2,27,32,32)
    const float* res0_bn = (const float*)d_in[2];   // (2,2,4,32)
    const float* down_bn = (const float*)d_in[3];   // (4,32)
    const float* down_W  = (const float*)d_in[4];   // (8,32,64)
    const float* res1_W  = (const float*)d_in[5];   // (2,2,27,64,64)
    const float* res1_bn = (const float*)d_in[6];   // (2,2,4,64)
    const float* up_bn   = (const float*)d_in[7];   // (4,64)
    const float* up_W    = (const float*)d_in[8];   // (8,64,32)
    const float* t0_bn1  = (const float*)d_in[9];   // (4,64)
    const float* t0_W1   = (const float*)d_in[10];  // (27,64,32)
    const float* t0_bn2  = (const float*)d_in[11];  // (4,32)
    const float* t0_W2   = (const float*)d_in[12];  // (27,32,32)
    const float* t0_Wsc  = (const float*)d_in[13];  // (64,32)
    const float* t1_W    = (const float*)d_in[14];  // (2,27,32,32)
    const float* t1_bn   = (const float*)d_in[15];  // (2,4,32)
    const int* s0i = (const int*)d_in[16];
    const int* s0o = (const int*)d_in[17];
    const int* s1i = (const int*)d_in[18];
    const int* s1o = (const int*)d_in[19];
    const int* dni = (const int*)d_in[20];
    const int* dno = (const int*)d_in[21];
    const int* n1p = (const int*)d_in[22];          // device scalar n1

    const int n0 = in_sizes[0] / 32;
    const int P0 = in_sizes[16] / 27;
    const int P1 = in_sizes[18] / 27;
    const int Pd = in_sizes[20] / 8;

    // ---- workspace layout ----
    const size_t bufN = (size_t)n0 * 64;
    float* B0 = (float*)d_ws;
    float* B1 = B0 + bufN;
    float* B2 = B1 + bufN;
    float* B3 = B2 + bufN;
    float* B4 = B3 + bufN;
    int* T0 = (int*)(B4 + bufN);        // [27][n0] subm level-0
    int* T1 = T0 + (size_t)27 * n0;     // [27][n0] subm level-1 (bound n0)
    int* Td = T1 + (size_t)27 * n0;     // [8][n0]  down gather
    int* Tu = Td + (size_t)8 * n0;      // [8][n0]  up gather

    // ---- build gather tables ----
    auto msetT = [&](int* T, int K) {
        hipMemsetAsync(T, 0xFF, (size_t)K * n0 * 4, stream);  // -1
    };
    msetT(T0, 27); msetT(T1, 27); msetT(Td, 8); msetT(Tu, 8);
    auto build = [&](const int* pin, const int* pout, int K, int P,
                     int padc, const int* padd, int* T) {
        hipLaunchKernelGGL(build_table_kernel, dim3((K * P + 255) / 256),
                           dim3(256), 0, stream, pin, pout, K, P, padc, padd, n0, T);
    };
    build(s0i, s0o, 27, P0, n0, nullptr, T0);
    build(s1i, s1o, 27, P1, 0, n1p, T1);
    build(dni, dno, 8, Pd, n0, nullptr, Td);
    build(dno, dni, 8, Pd, 0, n1p, Tu);   // up: roles swapped, pad via n1

    const int g32 = (n0 * 32 + 255) / 256;
    const int g64 = (n0 * 64 + 255) / 256;

    auto bnrelu32 = [&](const float* x, const float* bn, float* out, const int* ndev) {
        hipLaunchKernelGGL((bn_relu_kernel<32>), dim3(g32), dim3(256), 0, stream,
                           x, bn, out, n0, ndev);
    };
    auto bnrelu64 = [&](const float* x, const float* bn, float* out, const int* ndev) {
        hipLaunchKernelGGL((bn_relu_kernel<64>), dim3(g64), dim3(256), 0, stream,
                           x, bn, out, n0, ndev);
    };

    constexpr int R = 8;
    auto conv3232 = [&](const float* x, const float* W, const int* T,
                        const float* add, float* out) {
        const int rpb = (256 / 32) * R;  // 64 rows/block
        hipLaunchKernelGGL((gconv_kernel<32, 32, 27, R>), dim3((n0 + rpb - 1) / rpb),
                           dim3(256), 0, stream, x, W, T, n0, add, out, n0, nullptr);
    };
    auto conv6464 = [&](const float* x, const float* W, const float* add, float* out) {
        const int rpb = (256 / 64) * R;  // 32 rows/block
        hipLaunchKernelGGL((gconv_kernel<64, 64, 27, R>), dim3((n0 + rpb - 1) / rpb),
                           dim3(256), 0, stream, x, W, T1, n0, add, out, 0, n1p);
    };

    // ---- res0 block 0 ----
    bnrelu32(feats, res0_bn + 0 * 128, B0, nullptr);
    conv3232(B0, res0_W + 0 * 27 * 1024, T0, nullptr, B1);
    bnrelu32(B1, res0_bn + 1 * 128, B0, nullptr);
    conv3232(B0, res0_W + 1 * 27 * 1024, T0, feats, B2);

    // ---- res0 block 1 ----
    bnrelu32(B2, res0_bn + 2 * 128, B0, nullptr);
    conv3232(B0, res0_W + 2 * 27 * 1024, T0, nullptr, B1);
    bnrelu32(B1, res0_bn + 3 * 128, B0, nullptr);
    conv3232(B0, res0_W + 3 * 27 * 1024, T0, B2, B3);
    // identity = B3

    // ---- downsample: B3 -> B1 (n1 x 64) ----
    bnrelu32(B3, down_bn, B0, nullptr);
    {
        const int rpb = (256 / 64) * R;
        hipLaunchKernelGGL((gconv_kernel<32, 64, 8, R>), dim3((n0 + rpb - 1) / rpb),
                           dim3(256), 0, stream, B0, down_W, Td, n0, (const float*)nullptr,
                           B1, 0, n1p);
    }

    // ---- res1 block 0: B1 -> B4 ----
    bnrelu64(B1, res1_bn + 0 * 256, B0, n1p);
    conv6464(B0, res1_W + 0 * 27 * 4096, nullptr, B2);
    bnrelu64(B2, res1_bn + 1 * 256, B0, n1p);
    conv6464(B0, res1_W + 1 * 27 * 4096, B1, B4);

    // ---- res1 block 1: B4 -> B1 ----
    bnrelu64(B4, res1_bn + 2 * 256, B0, n1p);
    conv6464(B0, res1_W + 2 * 27 * 4096, nullptr, B2);
    bnrelu64(B2, res1_bn + 3 * 256, B0, n1p);
    conv6464(B0, res1_W + 3 * 27 * 4096, B4, B1);

    // ---- upsample: B1 -> B2 (n0 x 32) ----
    bnrelu64(B1, up_bn, B0, n1p);
    {
        const int rpb = (256 / 32) * R;
        hipLaunchKernelGGL((gconv_kernel<64, 32, 8, R>), dim3((n0 + rpb - 1) / rpb),
                           dim3(256), 0, stream, B0, up_W, Tu, n0, (const float*)nullptr,
                           B2, n0, nullptr);
    }

    // ---- concat: B4 = [B3 | B2] ----
    hipLaunchKernelGGL(concat_kernel, dim3(g64), dim3(256), 0, stream, B3, B2, B4, n0);

    // ---- tail0 ----
    bnrelu64(B4, t0_bn1, B0, nullptr);
    {
        const int rpb = (256 / 32) * R;
        hipLaunchKernelGGL((gconv_kernel<64, 32, 27, R>), dim3((n0 + rpb - 1) / rpb),
                           dim3(256), 0, stream, B0, t0_W1, T0, n0, (const float*)nullptr,
                           B1, n0, nullptr);
    }
    bnrelu32(B1, t0_bn2, B0, nullptr);
    hipLaunchKernelGGL(dense_mm_kernel, dim3(g32), dim3(256), 0, stream, B4, t0_Wsc, B2, n0);
    conv3232(B0, t0_W2, T0, B2, B2);   // out[row]=acc+add[row], 1:1 thread:elem -> safe

    // ---- tail1 res block: B2 -> d_out ----
    float* outp = (float*)d_out;
    bnrelu32(B2, t1_bn + 0 * 128, B0, nullptr);
    conv3232(B0, t1_W + 0 * 27 * 1024, T0, nullptr, B1);
    bnrelu32(B1, t1_bn + 1 * 128, B0, nullptr);
    conv3232(B0, t1_W + 1 * 27 * 1024, T0, B2, outp);
}

// Round 5
// 770.224 us; speedup vs baseline: 5.1442x; 5.1442x over previous
//
#include <hip/hip_runtime.h>

#define EPS_BN 1e-4f

typedef _Float16 f16x8 __attribute__((ext_vector_type(8)));
typedef float f32x4 __attribute__((ext_vector_type(4)));

// ---------------------------------------------------------------------------
// bn_relu -> fp16: out = (half)relu((x - m) * (g * rsqrt(v+eps)) + b)
// bn layout [4][C]. n_dev (if non-null) overrides n_const (device n1).
// ---------------------------------------------------------------------------
template <int C>
__global__ __launch_bounds__(256) void bn_relu_kernel(
    const float* __restrict__ x, const float* __restrict__ bn,
    _Float16* __restrict__ out, int n_const, const int* __restrict__ n_dev)
{
    const int n = n_dev ? *n_dev : n_const;
    const long total = (long)n * C;
    const long i = (long)blockIdx.x * blockDim.x + threadIdx.x;
    if (i >= total) return;
    const int c = (int)(i & (C - 1));
    const float g = bn[c], b = bn[C + c], m = bn[2 * C + c], v = bn[3 * C + c];
    const float val = (x[i] - m) * (g * rsqrtf(v + EPS_BN)) + b;
    out[i] = (_Float16)fmaxf(val, 0.f);
}

// ---------------------------------------------------------------------------
// Build gather table: T[k*nb + pout[k,p]] = pin[k,p] for valid (non-pad) pairs.
// T pre-initialized to -1. Each (out,k) slot hit at most once.
// ---------------------------------------------------------------------------
__global__ __launch_bounds__(256) void build_table_kernel(
    const int* __restrict__ pin, const int* __restrict__ pout,
    int K, int P, int pad_const, const int* __restrict__ pad_dev,
    int nb, int* __restrict__ T)
{
    const int e = blockIdx.x * 256 + threadIdx.x;
    if (e >= K * P) return;
    const int pad = pad_dev ? *pad_dev : pad_const;
    const int in = pin[e];
    if (in == pad) return;
    const int k = e / P;
    T[(size_t)k * nb + pout[e]] = in;
}

// ---------------------------------------------------------------------------
// Weight convert+transpose: src [K][CIN][COUT] fp32 -> dst [K][COUT][CIN] fp16
// ---------------------------------------------------------------------------
__global__ __launch_bounds__(256) void wcvt_kernel(
    const float* __restrict__ src, _Float16* __restrict__ dst,
    int K, int CIN, int COUT)
{
    const int e = blockIdx.x * 256 + threadIdx.x;
    if (e >= K * CIN * COUT) return;
    const int k = e / (CIN * COUT), r = e % (CIN * COUT);
    const int ci = r / COUT, co = r % COUT;
    dst[(size_t)k * CIN * COUT + (size_t)co * CIN + ci] = (_Float16)src[e];
}

// ---------------------------------------------------------------------------
// MFMA gather conv: out[row] = sum_k x[T[k][row]] @ W[k]  (+ add[row])
// Wave = 16 output rows x COUT. mfma_f32_16x16x32_f16, fp32 accum.
// A-frag: lane holds x-row (lane&15), k = (lane>>4)*8 + 0..7  (16B load)
// B-frag: lane holds Wt col (lane&15), same k-range            (16B load)
// C/D: col = lane&15, row = (lane>>4)*4 + reg                  [m89]
// Invalid gather (T<0) -> zero-row pointer (cndmask), MFMA on zeros.
// ---------------------------------------------------------------------------
template <int CIN, int COUT, int K>
__global__ __launch_bounds__(256) void mconv_kernel(
    const _Float16* __restrict__ x, const _Float16* __restrict__ Wt,
    const int* __restrict__ T, int nb, const _Float16* __restrict__ zrow,
    const float* __restrict__ add, float* __restrict__ out,
    int n_const, const int* __restrict__ n_dev)
{
    const int n = n_dev ? *n_dev : n_const;
    const int wave = threadIdx.x >> 6;
    const int lane = threadIdx.x & 63;
    const int row0 = blockIdx.x * 64 + wave * 16;
    if (row0 >= n) return;                 // wave-uniform exit, no syncs used
    const int lrow = lane & 15;
    const int kgrp = lane >> 4;            // 0..3
    const int grow = row0 + lrow;          // A gather row for this lane
    const int koff = kgrp * 8;
    constexpr int NF = COUT / 16;
    constexpr int KK = CIN / 32;

    f32x4 acc[NF];
#pragma unroll
    for (int f = 0; f < NF; ++f) acc[f] = (f32x4)0.f;

    for (int k = 0; k < K; ++k) {
        const int t = (grow < n) ? T[(size_t)k * nb + grow] : -1;
        const _Float16* arow = (t >= 0) ? (x + (size_t)t * CIN) : zrow;
        const _Float16* wtap = Wt + (size_t)k * CIN * COUT;
#pragma unroll
        for (int kk = 0; kk < KK; ++kk) {
            const f16x8 av = *(const f16x8*)(arow + kk * 32 + koff);
#pragma unroll
            for (int f = 0; f < NF; ++f) {
                const f16x8 bv = *(const f16x8*)(wtap +
                    (size_t)(f * 16 + lrow) * CIN + kk * 32 + koff);
                acc[f] = __builtin_amdgcn_mfma_f32_16x16x32_f16(av, bv, acc[f], 0, 0, 0);
            }
        }
    }
#pragma unroll
    for (int f = 0; f < NF; ++f) {
#pragma unroll
        for (int i = 0; i < 4; ++i) {
            const int r = row0 + kgrp * 4 + i;
            if (r < n) {
                const size_t o = (size_t)r * COUT + f * 16 + lrow;
                float v = acc[f][i];
                if (add) v += add[o];
                out[o] = v;
            }
        }
    }
}

// ---------------------------------------------------------------------------
// concat: out[i][0:32] = a[i], out[i][32:64] = b[i]   (fp32)
// ---------------------------------------------------------------------------
__global__ __launch_bounds__(256) void concat_kernel(
    const float* __restrict__ a, const float* __restrict__ b,
    float* __restrict__ out, int n)
{
    const int i = blockIdx.x * 256 + threadIdx.x;
    if (i >= n * 64) return;
    const int row = i >> 6, c = i & 63;
    out[i] = (c < 32) ? a[row * 32 + c] : b[row * 32 + (c - 32)];
}

// ---------------------------------------------------------------------------
// dense matmul: out[n x 32] = x[n x 64] @ W[64 x 32]   (fp32 scalar)
// ---------------------------------------------------------------------------
__global__ __launch_bounds__(256) void dense_mm_kernel(
    const float* __restrict__ x, const float* __restrict__ W,
    float* __restrict__ out, int n)
{
    __shared__ float Wl[64 * 32];
    for (int i = threadIdx.x; i < 64 * 32; i += 256) Wl[i] = W[i];
    __syncthreads();
    const int idx = blockIdx.x * 256 + threadIdx.x;
    const int row = idx >> 5, c = idx & 31;
    if (row >= n) return;
    const float* xr = x + (size_t)row * 64;
    float acc = 0.f;
#pragma unroll
    for (int q = 0; q < 16; ++q) {
        const float4 xv = *(const float4*)(xr + 4 * q);
        acc = fmaf(xv.x, Wl[(4 * q + 0) * 32 + c], acc);
        acc = fmaf(xv.y, Wl[(4 * q + 1) * 32 + c], acc);
        acc = fmaf(xv.z, Wl[(4 * q + 2) * 32 + c], acc);
        acc = fmaf(xv.w, Wl[(4 * q + 3) * 32 + c], acc);
    }
    out[(size_t)row * 32 + c] = acc;
}

// ---------------------------------------------------------------------------

extern "C" void kernel_launch(void* const* d_in, const int* in_sizes, int n_in,
                              void* d_out, int out_size, void* d_ws, size_t ws_size,
                              hipStream_t stream)
{
    const float* feats   = (const float*)d_in[0];
    const float* res0_W  = (const float*)d_in[1];   // (2,2,27,32,32)
    const float* res0_bn = (const float*)d_in[2];   // (2,2,4,32)
    const float* down_bn = (const float*)d_in[3];   // (4,32)
    const float* down_W  = (const float*)d_in[4];   // (8,32,64)
    const float* res1_W  = (const float*)d_in[5];   // (2,2,27,64,64)
    const float* res1_bn = (const float*)d_in[6];   // (2,2,4,64)
    const float* up_bn   = (const float*)d_in[7];   // (4,64)
    const float* up_W    = (const float*)d_in[8];   // (8,64,32)
    const float* t0_bn1  = (const float*)d_in[9];   // (4,64)
    const float* t0_W1   = (const float*)d_in[10];  // (27,64,32)
    const float* t0_bn2  = (const float*)d_in[11];  // (4,32)
    const float* t0_W2   = (const float*)d_in[12];  // (27,32,32)
    const float* t0_Wsc  = (const float*)d_in[13];  // (64,32)
    const float* t1_W    = (const float*)d_in[14];  // (2,27,32,32)
    const float* t1_bn   = (const float*)d_in[15];  // (2,4,32)
    const int* s0i = (const int*)d_in[16];
    const int* s0o = (const int*)d_in[17];
    const int* s1i = (const int*)d_in[18];
    const int* s1o = (const int*)d_in[19];
    const int* dni = (const int*)d_in[20];
    const int* dno = (const int*)d_in[21];
    const int* n1p = (const int*)d_in[22];          // device scalar n1

    const int n0 = in_sizes[0] / 32;
    const int P0 = in_sizes[16] / 27;
    const int P1 = in_sizes[18] / 27;
    const int Pd = in_sizes[20] / 8;

    // ---- workspace layout (all chunks 16B-aligned) ----
    const size_t bufN = (size_t)n0 * 64;
    float* F0 = (float*)d_ws;
    float* F1 = F0 + bufN;
    float* F2 = F1 + bufN;
    float* F3 = F2 + bufN;
    float* F4 = F3 + bufN;
    int* T0 = (int*)(F4 + bufN);          // [27][n0]
    int* T1 = T0 + (size_t)27 * n0;       // [27][n0]
    int* Td = T1 + (size_t)27 * n0;       // [8][n0]
    int* Tu = Td + (size_t)8 * n0;        // [8][n0]
    _Float16* H = (_Float16*)(Tu + (size_t)8 * n0);  // [n0][64] fp16 activations
    _Float16* Wt_res0 = H + bufN;                    // 108*1024
    _Float16* Wt_down = Wt_res0 + 108 * 1024;        // 8*2048
    _Float16* Wt_res1 = Wt_down + 8 * 2048;          // 108*4096
    _Float16* Wt_up   = Wt_res1 + (size_t)108 * 4096;// 8*2048
    _Float16* Wt_t01  = Wt_up + 8 * 2048;            // 27*2048
    _Float16* Wt_t02  = Wt_t01 + 27 * 2048;          // 27*1024
    _Float16* Wt_t1   = Wt_t02 + 27 * 1024;          // 54*1024
    _Float16* zrow    = Wt_t1 + 54 * 1024;           // 64 zero halfs

    // ---- tables ----
    auto msetT = [&](int* T, int K) {
        hipMemsetAsync(T, 0xFF, (size_t)K * n0 * 4, stream);
    };
    msetT(T0, 27); msetT(T1, 27); msetT(Td, 8); msetT(Tu, 8);
    hipMemsetAsync(zrow, 0, 64 * sizeof(_Float16), stream);
    auto build = [&](const int* pin, const int* pout, int K, int P,
                     int padc, const int* padd, int* T) {
        hipLaunchKernelGGL(build_table_kernel, dim3((K * P + 255) / 256),
                           dim3(256), 0, stream, pin, pout, K, P, padc, padd, n0, T);
    };
    build(s0i, s0o, 27, P0, n0, nullptr, T0);
    build(s1i, s1o, 27, P1, 0, n1p, T1);
    build(dni, dno, 8, Pd, n0, nullptr, Td);
    build(dno, dni, 8, Pd, 0, n1p, Tu);

    // ---- weight convert+transpose ----
    auto wcvt = [&](const float* src, _Float16* dst, int K, int CI, int CO) {
        const int tot = K * CI * CO;
        hipLaunchKernelGGL(wcvt_kernel, dim3((tot + 255) / 256), dim3(256), 0,
                           stream, src, dst, K, CI, CO);
    };
    wcvt(res0_W, Wt_res0, 108, 32, 32);
    wcvt(down_W, Wt_down, 8, 32, 64);
    wcvt(res1_W, Wt_res1, 108, 64, 64);
    wcvt(up_W,   Wt_up,   8, 64, 32);
    wcvt(t0_W1,  Wt_t01, 27, 64, 32);
    wcvt(t0_W2,  Wt_t02, 27, 32, 32);
    wcvt(t1_W,   Wt_t1,  54, 32, 32);

    const int g32 = (n0 * 32 + 255) / 256;
    const int g64 = (n0 * 64 + 255) / 256;
    const int gmc = (n0 + 63) / 64;   // mconv grid (64 rows/block)

    auto bn32 = [&](const float* x, const float* bn, const int* ndev) {
        hipLaunchKernelGGL((bn_relu_kernel<32>), dim3(g32), dim3(256), 0, stream,
                           x, bn, H, n0, ndev);
    };
    auto bn64 = [&](const float* x, const float* bn, const int* ndev) {
        hipLaunchKernelGGL((bn_relu_kernel<64>), dim3(g64), dim3(256), 0, stream,
                           x, bn, H, n0, ndev);
    };
    auto mc3232 = [&](const _Float16* Wt, const int* T, const float* add,
                      float* out) {
        hipLaunchKernelGGL((mconv_kernel<32, 32, 27>), dim3(gmc), dim3(256), 0,
                           stream, H, Wt, T, n0, zrow, add, out, n0, nullptr);
    };
    auto mc6464 = [&](const _Float16* Wt, const float* add, float* out) {
        hipLaunchKernelGGL((mconv_kernel<64, 64, 27>), dim3(gmc), dim3(256), 0,
                           stream, H, Wt, T1, n0, zrow, add, out, 0, n1p);
    };

    // ---- res0 block 0 ----
    bn32(feats, res0_bn + 0 * 128, nullptr);
    mc3232(Wt_res0 + 0 * 27 * 1024, T0, nullptr, F1);
    bn32(F1, res0_bn + 1 * 128, nullptr);
    mc3232(Wt_res0 + 1 * 27 * 1024, T0, feats, F2);

    // ---- res0 block 1 ----
    bn32(F2, res0_bn + 2 * 128, nullptr);
    mc3232(Wt_res0 + 2 * 27 * 1024, T0, nullptr, F1);
    bn32(F1, res0_bn + 3 * 128, nullptr);
    mc3232(Wt_res0 + 3 * 27 * 1024, T0, F2, F3);
    // identity = F3

    // ---- downsample: F3 -> F1 (n1 x 64) ----
    bn32(F3, down_bn, nullptr);
    hipLaunchKernelGGL((mconv_kernel<32, 64, 8>), dim3(gmc), dim3(256), 0,
                       stream, H, Wt_down, Td, n0, zrow, (const float*)nullptr,
                       F1, 0, n1p);

    // ---- res1 block 0: F1 -> F4 ----
    bn64(F1, res1_bn + 0 * 256, n1p);
    mc6464(Wt_res1 + 0 * 27 * 4096, nullptr, F2);
    bn64(F2, res1_bn + 1 * 256, n1p);
    mc6464(Wt_res1 + 1 * 27 * 4096, F1, F4);

    // ---- res1 block 1: F4 -> F1 ----
    bn64(F4, res1_bn + 2 * 256, n1p);
    mc6464(Wt_res1 + 2 * 27 * 4096, nullptr, F2);
    bn64(F2, res1_bn + 3 * 256, n1p);
    mc6464(Wt_res1 + 3 * 27 * 4096, F4, F1);

    // ---- upsample: F1 -> F2 (n0 x 32) ----
    bn64(F1, up_bn, n1p);
    hipLaunchKernelGGL((mconv_kernel<64, 32, 8>), dim3(gmc), dim3(256), 0,
                       stream, H, Wt_up, Tu, n0, zrow, (const float*)nullptr,
                       F2, n0, nullptr);

    // ---- concat: F4 = [F3 | F2] ----
    hipLaunchKernelGGL(concat_kernel, dim3(g64), dim3(256), 0, stream, F3, F2, F4, n0);

    // ---- tail0 ----
    bn64(F4, t0_bn1, nullptr);
    hipLaunchKernelGGL((mconv_kernel<64, 32, 27>), dim3(gmc), dim3(256), 0,
                       stream, H, Wt_t01, T0, n0, zrow, (const float*)nullptr,
                       F1, n0, nullptr);
    bn32(F1, t0_bn2, nullptr);
    hipLaunchKernelGGL(dense_mm_kernel, dim3(g32), dim3(256), 0, stream,
                       F4, t0_Wsc, F2, n0);
    mc3232(Wt_t02, T0, F2, F2);   // out = conv + shortcut (1:1 elem, safe)

    // ---- tail1 res block: F2 -> d_out ----
    float* outp = (float*)d_out;
    bn32(F2, t1_bn + 0 * 128, nullptr);
    mc3232(Wt_t1 + 0 * 27 * 1024, T0, nullptr, F1);
    bn32(F1, t1_bn + 1 * 128, nullptr);
    mc3232(Wt_t1 + 1 * 27 * 1024, T0, F2, outp);
}

// Round 6
// 661.125 us; speedup vs baseline: 5.9931x; 1.1650x over previous
//
#include <hip/hip_runtime.h>

#define EPS_BN 1e-4f

typedef _Float16 f16x8 __attribute__((ext_vector_type(8)));
typedef float f32x4 __attribute__((ext_vector_type(4)));

// ---------------------------------------------------------------------------
// bn_relu -> fp16 (standalone; only used for the very first layer input)
// bn layout [4][C].
// ---------------------------------------------------------------------------
template <int C>
__global__ __launch_bounds__(256) void bn_relu_kernel(
    const float* __restrict__ x, const float* __restrict__ bn,
    _Float16* __restrict__ out, int n_const, const int* __restrict__ n_dev)
{
    const int n = n_dev ? *n_dev : n_const;
    const long total = (long)n * C;
    const long i = (long)blockIdx.x * blockDim.x + threadIdx.x;
    if (i >= total) return;
    const int c = (int)(i & (C - 1));
    const float g = bn[c], b = bn[C + c], m = bn[2 * C + c], v = bn[3 * C + c];
    const float val = (x[i] - m) * (g * rsqrtf(v + EPS_BN)) + b;
    out[i] = (_Float16)fmaxf(val, 0.f);
}

// ---------------------------------------------------------------------------
// Build row-major gather table: Trow[pout[k,p]*KPAD + k] = pin[k,p]
// (pre-initialized to -1; skip pad pairs)
// ---------------------------------------------------------------------------
__global__ __launch_bounds__(256) void build_table_kernel(
    const int* __restrict__ pin, const int* __restrict__ pout,
    int K, int P, int pad_const, const int* __restrict__ pad_dev,
    int KPAD, int* __restrict__ T)
{
    const int e = blockIdx.x * 256 + threadIdx.x;
    if (e >= K * P) return;
    const int pad = pad_dev ? *pad_dev : pad_const;
    const int in = pin[e];
    if (in == pad) return;
    const int k = e / P;
    T[(size_t)pout[e] * KPAD + k] = in;
}

// ---------------------------------------------------------------------------
// Weight convert+transpose: src [K][CIN][COUT] fp32 -> dst [K][COUT][CIN] fp16
// ---------------------------------------------------------------------------
__global__ __launch_bounds__(256) void wcvt_kernel(
    const float* __restrict__ src, _Float16* __restrict__ dst,
    int K, int CIN, int COUT)
{
    const int e = blockIdx.x * 256 + threadIdx.x;
    if (e >= K * CIN * COUT) return;
    const int k = e / (CIN * COUT), r = e % (CIN * COUT);
    const int ci = r / COUT, co = r % COUT;
    dst[(size_t)k * CIN * COUT + (size_t)co * CIN + ci] = (_Float16)src[e];
}

// ---------------------------------------------------------------------------
// MFMA gather conv, 2-deep software-pipelined over taps.
//   acc[row,cout] = sum_k x[Trow[row][k]] @ W[k];  v = acc (+ add)
//   fout (fp32, optional) = v;  hout (fp16, optional) = bn_relu(v) [bnx]
// Wave = 16 rows x COUT. mfma_f32_16x16x32_f16.
// A: lane holds x-row (lane&15), k-slice (lane>>4)*8.. (16B)
// B: lane holds Wt col (lane&15), same k-slice (16B)
// C/D: col = lane&15, row = (lane>>4)*4 + reg   [m89]
// ---------------------------------------------------------------------------
template <int CIN, int COUT, int K, int KPAD>
__global__ __launch_bounds__(256) void mconv_kernel(
    const _Float16* __restrict__ x, const _Float16* __restrict__ Wt,
    const int* __restrict__ Trow, const _Float16* __restrict__ zrow,
    const float* __restrict__ add, float* __restrict__ fout,
    const float* __restrict__ bnx, _Float16* __restrict__ hout,
    int n_const, const int* __restrict__ n_dev)
{
    const int n = n_dev ? *n_dev : n_const;
    const int wave = threadIdx.x >> 6;
    const int lane = threadIdx.x & 63;
    const int row0 = blockIdx.x * 64 + wave * 16;
    if (row0 >= n) return;              // wave-uniform exit; kernel has no syncs
    const int lrow = lane & 15;
    const int kgrp = lane >> 4;         // 0..3
    const int koff = kgrp * 8;
    const int grow = row0 + lrow;
    constexpr int KK = CIN / 32, NF = COUT / 16;

    // ---- load all tap indices for this lane's gather row (int4 chunks) ----
    int tk[KPAD];
    {
        const int4* tp = (const int4*)(Trow + (size_t)grow * KPAD);
        const bool gv = grow < n;
#pragma unroll
        for (int j = 0; j < KPAD / 4; ++j) {
            const int4 q = gv ? tp[j] : make_int4(-1, -1, -1, -1);
            tk[4 * j + 0] = q.x; tk[4 * j + 1] = q.y;
            tk[4 * j + 2] = q.z; tk[4 * j + 3] = q.w;
        }
    }

    f32x4 acc[NF];
#pragma unroll
    for (int f = 0; f < NF; ++f) acc[f] = (f32x4)0.f;

    f16x8 a0[KK], a1[KK], b0[KK][NF], b1[KK][NF];

    auto Aload = [&](int k, f16x8 (&a)[KK]) {   // k is compile-time after inline
        const int t = tk[k];
        const _Float16* ar = (t >= 0) ? (x + (size_t)t * CIN + koff) : (zrow + koff);
#pragma unroll
        for (int kk = 0; kk < KK; ++kk)
            a[kk] = *(const f16x8*)(ar + kk * 32);
    };
    auto Bload = [&](int k, f16x8 (&b)[KK][NF]) {
        const _Float16* wb = Wt + ((size_t)k * COUT + lrow) * CIN + koff;
#pragma unroll
        for (int kk = 0; kk < KK; ++kk)
#pragma unroll
            for (int f = 0; f < NF; ++f)
                b[kk][f] = *(const f16x8*)(wb + (size_t)f * 16 * CIN + kk * 32);
    };
    auto Mfma = [&](f16x8 (&a)[KK], f16x8 (&b)[KK][NF]) {
#pragma unroll
        for (int kk = 0; kk < KK; ++kk)
#pragma unroll
            for (int f = 0; f < NF; ++f)
                acc[f] = __builtin_amdgcn_mfma_f32_16x16x32_f16(
                    a[kk], b[kk][f], acc[f], 0, 0, 0);
    };

    // ---- 2-deep pipelined tap loop (all k compile-time; no reg moves) ----
    Aload(0, a0); Bload(0, b0);
#pragma unroll
    for (int k = 0; k < K; k += 2) {
        if (k + 1 < K) { Aload(k + 1, a1); Bload(k + 1, b1); }
        Mfma(a0, b0);
        if (k + 1 < K) {
            if (k + 2 < K) { Aload(k + 2, a0); Bload(k + 2, b0); }
            Mfma(a1, b1);
        }
    }

    // ---- epilogue: add, fp32 out, fused bn_relu fp16 out ----
#pragma unroll
    for (int f = 0; f < NF; ++f) {
        const int c = f * 16 + lrow;
        float sc = 0.f, mm = 0.f, be = 0.f;
        if (hout) {
            const float g = bnx[c];
            be = bnx[COUT + c];
            mm = bnx[2 * COUT + c];
            const float va = bnx[3 * COUT + c];
            sc = g * rsqrtf(va + EPS_BN);
        }
#pragma unroll
        for (int i = 0; i < 4; ++i) {
            const int r = row0 + kgrp * 4 + i;
            if (r < n) {
                const size_t o = (size_t)r * COUT + c;
                float v = acc[f][i];
                if (add) v += add[o];
                if (fout) fout[o] = v;
                if (hout) hout[o] = (_Float16)fmaxf((v - mm) * sc + be, 0.f);
            }
        }
    }
}

// ---------------------------------------------------------------------------
// concat + fused bn_relu: fout[i] = concat(a,b); hout[i] = bn_relu(fout[i])
// ---------------------------------------------------------------------------
__global__ __launch_bounds__(256) void concat_bn_kernel(
    const float* __restrict__ a, const float* __restrict__ b,
    float* __restrict__ fout, const float* __restrict__ bnx,
    _Float16* __restrict__ hout, int n)
{
    const int i = blockIdx.x * 256 + threadIdx.x;
    if (i >= n * 64) return;
    const int row = i >> 6, c = i & 63;
    const float v = (c < 32) ? a[row * 32 + c] : b[row * 32 + (c - 32)];
    fout[i] = v;
    const float g = bnx[c], be = bnx[64 + c], m = bnx[128 + c], va = bnx[192 + c];
    hout[i] = (_Float16)fmaxf((v - m) * (g * rsqrtf(va + EPS_BN)) + be, 0.f);
}

// ---------------------------------------------------------------------------
// dense matmul: out[n x 32] = x[n x 64] @ W[64 x 32]   (fp32 scalar)
// ---------------------------------------------------------------------------
__global__ __launch_bounds__(256) void dense_mm_kernel(
    const float* __restrict__ x, const float* __restrict__ W,
    float* __restrict__ out, int n)
{
    __shared__ float Wl[64 * 32];
    for (int i = threadIdx.x; i < 64 * 32; i += 256) Wl[i] = W[i];
    __syncthreads();
    const int idx = blockIdx.x * 256 + threadIdx.x;
    const int row = idx >> 5, c = idx & 31;
    if (row >= n) return;
    const float* xr = x + (size_t)row * 64;
    float acc = 0.f;
#pragma unroll
    for (int q = 0; q < 16; ++q) {
        const float4 xv = *(const float4*)(xr + 4 * q);
        acc = fmaf(xv.x, Wl[(4 * q + 0) * 32 + c], acc);
        acc = fmaf(xv.y, Wl[(4 * q + 1) * 32 + c], acc);
        acc = fmaf(xv.z, Wl[(4 * q + 2) * 32 + c], acc);
        acc = fmaf(xv.w, Wl[(4 * q + 3) * 32 + c], acc);
    }
    out[(size_t)row * 32 + c] = acc;
}

// ---------------------------------------------------------------------------

extern "C" void kernel_launch(void* const* d_in, const int* in_sizes, int n_in,
                              void* d_out, int out_size, void* d_ws, size_t ws_size,
                              hipStream_t stream)
{
    const float* feats   = (const float*)d_in[0];
    const float* res0_W  = (const float*)d_in[1];   // (2,2,27,32,32)
    const float* res0_bn = (const float*)d_in[2];   // (2,2,4,32)
    const float* down_bn = (const float*)d_in[3];   // (4,32)
    const float* down_W  = (const float*)d_in[4];   // (8,32,64)
    const float* res1_W  = (const float*)d_in[5];   // (2,2,27,64,64)
    const float* res1_bn = (const float*)d_in[6];   // (2,2,4,64)
    const float* up_bn   = (const float*)d_in[7];   // (4,64)
    const float* up_W    = (const float*)d_in[8];   // (8,64,32)
    const float* t0_bn1  = (const float*)d_in[9];   // (4,64)
    const float* t0_W1   = (const float*)d_in[10];  // (27,64,32)
    const float* t0_bn2  = (const float*)d_in[11];  // (4,32)
    const float* t0_W2   = (const float*)d_in[12];  // (27,32,32)
    const float* t0_Wsc  = (const float*)d_in[13];  // (64,32)
    const float* t1_W    = (const float*)d_in[14];  // (2,27,32,32)
    const float* t1_bn   = (const float*)d_in[15];  // (2,4,32)
    const int* s0i = (const int*)d_in[16];
    const int* s0o = (const int*)d_in[17];
    const int* s1i = (const int*)d_in[18];
    const int* s1o = (const int*)d_in[19];
    const int* dni = (const int*)d_in[20];
    const int* dno = (const int*)d_in[21];
    const int* n1p = (const int*)d_in[22];          // device scalar n1

    const int n0 = in_sizes[0] / 32;
    const int P0 = in_sizes[16] / 27;
    const int P1 = in_sizes[18] / 27;
    const int Pd = in_sizes[20] / 8;

    // ---- workspace layout (all chunks 16B-aligned) ----
    const size_t bufN = (size_t)n0 * 64;
    float* F1 = (float*)d_ws;
    float* F2 = F1 + bufN;
    float* F3 = F2 + bufN;
    float* F4 = F3 + bufN;
    _Float16* Ha = (_Float16*)(F4 + bufN);           // [n0][<=64] fp16 ping
    _Float16* Hb = Ha + bufN;                        // pong
    int* T0r = (int*)(Hb + bufN);                    // [n0][28]
    int* T1r = T0r + (size_t)n0 * 28;                // [n0][28]
    int* Tdr = T1r + (size_t)n0 * 28;                // [n0][8]
    int* Tur = Tdr + (size_t)n0 * 8;                 // [n0][8]
    _Float16* Wt_res0 = (_Float16*)(Tur + (size_t)n0 * 8);  // 108*1024
    _Float16* Wt_down = Wt_res0 + 108 * 1024;        // 8*2048
    _Float16* Wt_res1 = Wt_down + 8 * 2048;          // 108*4096
    _Float16* Wt_up   = Wt_res1 + (size_t)108 * 4096;// 8*2048
    _Float16* Wt_t01  = Wt_up + 8 * 2048;            // 27*2048
    _Float16* Wt_t02  = Wt_t01 + 27 * 2048;          // 27*1024
    _Float16* Wt_t1   = Wt_t02 + 27 * 1024;          // 54*1024
    _Float16* zrow    = Wt_t1 + 54 * 1024;           // 64 zero halfs

    // ---- gather tables (row-major, padded K) ----
    hipMemsetAsync(T0r, 0xFF, (size_t)n0 * 28 * 4, stream);
    hipMemsetAsync(T1r, 0xFF, (size_t)n0 * 28 * 4, stream);
    hipMemsetAsync(Tdr, 0xFF, (size_t)n0 * 8 * 4, stream);
    hipMemsetAsync(Tur, 0xFF, (size_t)n0 * 8 * 4, stream);
    hipMemsetAsync(zrow, 0, 64 * sizeof(_Float16), stream);
    auto build = [&](const int* pin, const int* pout, int K, int P,
                     int padc, const int* padd, int KPAD, int* T) {
        hipLaunchKernelGGL(build_table_kernel, dim3((K * P + 255) / 256),
                           dim3(256), 0, stream, pin, pout, K, P, padc, padd,
                           KPAD, T);
    };
    build(s0i, s0o, 27, P0, n0, nullptr, 28, T0r);
    build(s1i, s1o, 27, P1, 0, n1p, 28, T1r);
    build(dni, dno, 8, Pd, n0, nullptr, 8, Tdr);
    build(dno, dni, 8, Pd, 0, n1p, 8, Tur);   // up: roles swapped

    // ---- weight convert+transpose ----
    auto wcvt = [&](const float* src, _Float16* dst, int K, int CI, int CO) {
        const int tot = K * CI * CO;
        hipLaunchKernelGGL(wcvt_kernel, dim3((tot + 255) / 256), dim3(256), 0,
                           stream, src, dst, K, CI, CO);
    };
    wcvt(res0_W, Wt_res0, 108, 32, 32);
    wcvt(down_W, Wt_down, 8, 32, 64);
    wcvt(res1_W, Wt_res1, 108, 64, 64);
    wcvt(up_W,   Wt_up,   8, 64, 32);
    wcvt(t0_W1,  Wt_t01, 27, 64, 32);
    wcvt(t0_W2,  Wt_t02, 27, 32, 32);
    wcvt(t1_W,   Wt_t1,  54, 32, 32);

    const int g32 = (n0 * 32 + 255) / 256;
    const int g64 = (n0 * 64 + 255) / 256;
    const int gmc = (n0 + 63) / 64;   // mconv grid (64 rows/block)

    auto mc3232 = [&](const _Float16* xin, const _Float16* Wtp, const int* T,
                      const float* add, float* fo, const float* bn, _Float16* ho,
                      int nc, const int* nd) {
        hipLaunchKernelGGL((mconv_kernel<32, 32, 27, 28>), dim3(gmc), dim3(256),
                           0, stream, xin, Wtp, T, zrow, add, fo, bn, ho, nc, nd);
    };
    auto mc6464 = [&](const _Float16* xin, const _Float16* Wtp,
                      const float* add, float* fo, const float* bn, _Float16* ho) {
        hipLaunchKernelGGL((mconv_kernel<64, 64, 27, 28>), dim3(gmc), dim3(256),
                           0, stream, xin, Wtp, T1r, zrow, add, fo, bn, ho, 0, n1p);
    };

    // 0: first bn_relu (feats -> Ha)
    hipLaunchKernelGGL((bn_relu_kernel<32>), dim3(g32), dim3(256), 0, stream,
                       feats, res0_bn + 0 * 128, Ha, n0, nullptr);
    // 1: res0.0 conv0: Ha -> Hb
    mc3232(Ha, Wt_res0 + 0 * 27 * 1024, T0r, nullptr, nullptr,
           res0_bn + 1 * 128, Hb, n0, nullptr);
    // 2: res0.0 conv1 (+feats): Hb -> F2, Ha
    mc3232(Hb, Wt_res0 + 1 * 27 * 1024, T0r, feats, F2,
           res0_bn + 2 * 128, Ha, n0, nullptr);
    // 3: res0.1 conv0: Ha -> Hb
    mc3232(Ha, Wt_res0 + 2 * 27 * 1024, T0r, nullptr, nullptr,
           res0_bn + 3 * 128, Hb, n0, nullptr);
    // 4: res0.1 conv1 (+F2): Hb -> F3 (identity), Ha [bn=down_bn]
    mc3232(Hb, Wt_res0 + 3 * 27 * 1024, T0r, F2, F3, down_bn, Ha, n0, nullptr);
    // 5: down conv: Ha -> F1 (n1 x 64), Hb [bn=res1_bn 0.0]
    hipLaunchKernelGGL((mconv_kernel<32, 64, 8, 8>), dim3(gmc), dim3(256), 0,
                       stream, Ha, Wt_down, Tdr, zrow, (const float*)nullptr, F1,
                       res1_bn + 0 * 256, Hb, 0, n1p);
    // 6: res1.0 conv0: Hb -> Ha
    mc6464(Hb, Wt_res1 + 0 * 27 * 4096, nullptr, nullptr, res1_bn + 1 * 256, Ha);
    // 7: res1.0 conv1 (+F1): Ha -> F4, Hb
    mc6464(Ha, Wt_res1 + 1 * 27 * 4096, F1, F4, res1_bn + 2 * 256, Hb);
    // 8: res1.1 conv0: Hb -> Ha
    mc6464(Hb, Wt_res1 + 2 * 27 * 4096, nullptr, nullptr, res1_bn + 3 * 256, Ha);
    // 9: res1.1 conv1 (+F4): Ha -> F1, Hb [bn=up_bn]
    mc6464(Ha, Wt_res1 + 3 * 27 * 4096, F4, F1, up_bn, Hb);
    // 10: up conv: Hb(level1) -> F2 (n0 x 32), no hout
    hipLaunchKernelGGL((mconv_kernel<64, 32, 8, 8>), dim3(gmc), dim3(256), 0,
                       stream, Hb, Wt_up, Tur, zrow, (const float*)nullptr, F2,
                       (const float*)nullptr, (_Float16*)nullptr, n0, nullptr);
    // 11: concat+bn: [F3|F2] -> F4 fp32, Ha fp16 [bn=t0_bn1]
    hipLaunchKernelGGL(concat_bn_kernel, dim3(g64), dim3(256), 0, stream,
                       F3, F2, F4, t0_bn1, Ha, n0);
    // 12: tail0 conv1 (64->32): Ha -> Hb [bn=t0_bn2]
    hipLaunchKernelGGL((mconv_kernel<64, 32, 27, 28>), dim3(gmc), dim3(256), 0,
                       stream, Ha, Wt_t01, T0r, zrow, (const float*)nullptr,
                       (float*)nullptr, t0_bn2, Hb, n0, nullptr);
    // 13: shortcut: F2 = F4 @ Wsc
    hipLaunchKernelGGL(dense_mm_kernel, dim3(g32), dim3(256), 0, stream,
                       F4, t0_Wsc, F2, n0);
    // 14: tail0 conv2 (+F2): Hb -> F2, Ha [bn=t1_bn0]  (in-place add safe: 1:1)
    mc3232(Hb, Wt_t02, T0r, F2, F2, t1_bn + 0 * 128, Ha, n0, nullptr);
    // 15: tail1 conv0: Ha -> Hb
    mc3232(Ha, Wt_t1 + 0 * 27 * 1024, T0r, nullptr, nullptr,
           t1_bn + 1 * 128, Hb, n0, nullptr);
    // 16: tail1 conv1 (+F2): Hb -> d_out
    mc3232(Hb, Wt_t1 + 1 * 27 * 1024, T0r, F2, (float*)d_out,
           nullptr, nullptr, n0, nullptr);
}

// Round 7
// 655.821 us; speedup vs baseline: 6.0416x; 1.0081x over previous
//
#include <hip/hip_runtime.h>

#define EPS_BN 1e-4f

typedef _Float16 f16x8 __attribute__((ext_vector_type(8)));
typedef float f32x4 __attribute__((ext_vector_type(4)));

// ---------------------------------------------------------------------------
// bn_relu -> fp16 (standalone; only for the first layer input)
// ---------------------------------------------------------------------------
template <int C>
__global__ __launch_bounds__(256) void bn_relu_kernel(
    const float* __restrict__ x, const float* __restrict__ bn,
    _Float16* __restrict__ out, int n_const, const int* __restrict__ n_dev)
{
    const int n = n_dev ? *n_dev : n_const;
    const long total = (long)n * C;
    const long i = (long)blockIdx.x * blockDim.x + threadIdx.x;
    if (i >= total) return;
    const int c = (int)(i & (C - 1));
    const float g = bn[c], b = bn[C + c], m = bn[2 * C + c], v = bn[3 * C + c];
    const float val = (x[i] - m) * (g * rsqrtf(v + EPS_BN)) + b;
    out[i] = (_Float16)fmaxf(val, 0.f);
}

// ---------------------------------------------------------------------------
// Build row-major gather table: Trow[pout[k,p]*KPAD + k] = pin[k,p]
// ---------------------------------------------------------------------------
__global__ __launch_bounds__(256) void build_table_kernel(
    const int* __restrict__ pin, const int* __restrict__ pout,
    int K, int P, int pad_const, const int* __restrict__ pad_dev,
    int KPAD, int* __restrict__ T)
{
    const int e = blockIdx.x * 256 + threadIdx.x;
    if (e >= K * P) return;
    const int pad = pad_dev ? *pad_dev : pad_const;
    const int in = pin[e];
    if (in == pad) return;
    const int k = e / P;
    T[(size_t)pout[e] * KPAD + k] = in;
}

// ---------------------------------------------------------------------------
// Weight convert+transpose: src [K][CIN][COUT] fp32 -> dst [K][COUT][CIN] fp16
// ---------------------------------------------------------------------------
__global__ __launch_bounds__(256) void wcvt_kernel(
    const float* __restrict__ src, _Float16* __restrict__ dst,
    int K, int CIN, int COUT)
{
    const int e = blockIdx.x * 256 + threadIdx.x;
    if (e >= K * CIN * COUT) return;
    const int k = e / (CIN * COUT), r = e % (CIN * COUT);
    const int ci = r / COUT, co = r % COUT;
    dst[(size_t)k * CIN * COUT + (size_t)co * CIN + ci] = (_Float16)src[e];
}

// ---------------------------------------------------------------------------
// MFMA gather conv, TAP-SPLIT: block = 16 rows, 4 waves; wave w owns taps
// [w*TPW, (w+1)*TPW). Partials reduced via padded LDS, single epilogue.
//   v = sum_k x[Trow[row][k]] @ W[k] (+ add);  fout = v;  hout = bn_relu(v)
// Wave frag: A lane = x-row (lane&15), k-slice (lane>>4)*8 (16B load)
//            B lane = Wt col (lane&15), same k-slice
//            C/D: col = lane&15, row = (lane>>4)*4 + reg   [m89]
// ---------------------------------------------------------------------------
template <int CIN, int COUT, int K, int KPAD>
__global__ __launch_bounds__(256, 4) void mconv_kernel(
    const _Float16* __restrict__ x, const _Float16* __restrict__ Wt,
    const int* __restrict__ Trow, const _Float16* __restrict__ zrow,
    const float* __restrict__ add, float* __restrict__ fout,
    const float* __restrict__ bnx, _Float16* __restrict__ hout,
    int n_const, const int* __restrict__ n_dev)
{
    constexpr int NW = 4;
    constexpr int TPW = (K + NW - 1) / NW;   // taps per wave (7 or 2)
    constexpr int KK = CIN / 32, NF = COUT / 16;
    constexpr int RST = COUT + 4;            // padded LDS row stride (floats)
    __shared__ float red[NW * 16 * RST];

    const int n = n_dev ? *n_dev : n_const;
    const int row0 = blockIdx.x * 16;
    if (row0 >= n) return;                   // block-uniform exit (pre-sync)
    const int wave = threadIdx.x >> 6, lane = threadIdx.x & 63;
    const int lrow = lane & 15, kgrp = lane >> 4, koff = kgrp * 8;
    const int grow = row0 + lrow;
    const int kb = wave * TPW;

    // tap indices for this wave's slice of this lane's row
    int tk[TPW];
#pragma unroll
    for (int j = 0; j < TPW; ++j) {
        const int k = kb + j;
        tk[j] = (grow < n && k < K) ? Trow[(size_t)grow * KPAD + k] : -1;
    }

    f32x4 acc[NF];
#pragma unroll
    for (int f = 0; f < NF; ++f) acc[f] = (f32x4)0.f;

    f16x8 a0[KK], a1[KK];
    auto Aload = [&](int j, f16x8 (&a)[KK]) {
        const int t = tk[j];
        const _Float16* ar = (t >= 0) ? (x + (size_t)t * CIN + koff) : (zrow + koff);
#pragma unroll
        for (int kk = 0; kk < KK; ++kk) a[kk] = *(const f16x8*)(ar + kk * 32);
    };
    auto MfmaTap = [&](int j, f16x8 (&a)[KK]) {
        const int kc = (kb + j < K) ? (kb + j) : (K - 1);  // A=0 when clamped
        const _Float16* wb = Wt + ((size_t)kc * COUT + lrow) * CIN + koff;
#pragma unroll
        for (int kk = 0; kk < KK; ++kk)
#pragma unroll
            for (int f = 0; f < NF; ++f) {
                const f16x8 bv = *(const f16x8*)(wb + (size_t)f * 16 * CIN + kk * 32);
                acc[f] = __builtin_amdgcn_mfma_f32_16x16x32_f16(a[kk], bv, acc[f],
                                                                0, 0, 0);
            }
    };

    // 2-deep A-prefetch over this wave's taps
    Aload(0, a0);
#pragma unroll
    for (int j = 0; j < TPW; j += 2) {
        if (j + 1 < TPW) Aload(j + 1, a1);
        MfmaTap(j, a0);
        if (j + 1 < TPW) {
            if (j + 2 < TPW) Aload(j + 2, a0);
            MfmaTap(j + 1, a1);
        }
    }

    // partials -> LDS
#pragma unroll
    for (int f = 0; f < NF; ++f)
#pragma unroll
        for (int i = 0; i < 4; ++i)
            red[(wave * 16 + kgrp * 4 + i) * RST + f * 16 + lrow] = acc[f][i];
    __syncthreads();

    // reduce 4 partials + epilogue (thread -> element, coalesced)
    constexpr int E = 16 * COUT / 256;
#pragma unroll
    for (int e = 0; e < E; ++e) {
        const int idx = threadIdx.x + e * 256;
        const int row = idx / COUT, c = idx % COUT;
        const int r = row0 + row;
        if (r >= n) continue;
        float v = red[(0 * 16 + row) * RST + c] + red[(1 * 16 + row) * RST + c]
                + red[(2 * 16 + row) * RST + c] + red[(3 * 16 + row) * RST + c];
        const size_t o = (size_t)r * COUT + c;
        if (add) v += add[o];
        if (fout) fout[o] = v;
        if (hout) {
            const float g = bnx[c], be = bnx[COUT + c];
            const float m = bnx[2 * COUT + c], va = bnx[3 * COUT + c];
            hout[o] = (_Float16)fmaxf((v - m) * (g * rsqrtf(va + EPS_BN)) + be, 0.f);
        }
    }
}

// ---------------------------------------------------------------------------
// concat + fused bn_relu: fout[i] = concat(a,b); hout[i] = bn_relu(fout[i])
// ---------------------------------------------------------------------------
__global__ __launch_bounds__(256) void concat_bn_kernel(
    const float* __restrict__ a, const float* __restrict__ b,
    float* __restrict__ fout, const float* __restrict__ bnx,
    _Float16* __restrict__ hout, int n)
{
    const int i = blockIdx.x * 256 + threadIdx.x;
    if (i >= n * 64) return;
    const int row = i >> 6, c = i & 63;
    const float v = (c < 32) ? a[row * 32 + c] : b[row * 32 + (c - 32)];
    fout[i] = v;
    const float g = bnx[c], be = bnx[64 + c], m = bnx[128 + c], va = bnx[192 + c];
    hout[i] = (_Float16)fmaxf((v - m) * (g * rsqrtf(va + EPS_BN)) + be, 0.f);
}

// ---------------------------------------------------------------------------
// dense matmul: out[n x 32] = x[n x 64] @ W[64 x 32]   (fp32 scalar)
// ---------------------------------------------------------------------------
__global__ __launch_bounds__(256) void dense_mm_kernel(
    const float* __restrict__ x, const float* __restrict__ W,
    float* __restrict__ out, int n)
{
    __shared__ float Wl[64 * 32];
    for (int i = threadIdx.x; i < 64 * 32; i += 256) Wl[i] = W[i];
    __syncthreads();
    const int idx = blockIdx.x * 256 + threadIdx.x;
    const int row = idx >> 5, c = idx & 31;
    if (row >= n) return;
    const float* xr = x + (size_t)row * 64;
    float acc = 0.f;
#pragma unroll
    for (int q = 0; q < 16; ++q) {
        const float4 xv = *(const float4*)(xr + 4 * q);
        acc = fmaf(xv.x, Wl[(4 * q + 0) * 32 + c], acc);
        acc = fmaf(xv.y, Wl[(4 * q + 1) * 32 + c], acc);
        acc = fmaf(xv.z, Wl[(4 * q + 2) * 32 + c], acc);
        acc = fmaf(xv.w, Wl[(4 * q + 3) * 32 + c], acc);
    }
    out[(size_t)row * 32 + c] = acc;
}

// ---------------------------------------------------------------------------

extern "C" void kernel_launch(void* const* d_in, const int* in_sizes, int n_in,
                              void* d_out, int out_size, void* d_ws, size_t ws_size,
                              hipStream_t stream)
{
    const float* feats   = (const float*)d_in[0];
    const float* res0_W  = (const float*)d_in[1];   // (2,2,27,32,32)
    const float* res0_bn = (const float*)d_in[2];   // (2,2,4,32)
    const float* down_bn = (const float*)d_in[3];   // (4,32)
    const float* down_W  = (const float*)d_in[4];   // (8,32,64)
    const float* res1_W  = (const float*)d_in[5];   // (2,2,27,64,64)
    const float* res1_bn = (const float*)d_in[6];   // (2,2,4,64)
    const float* up_bn   = (const float*)d_in[7];   // (4,64)
    const float* up_W    = (const float*)d_in[8];   // (8,64,32)
    const float* t0_bn1  = (const float*)d_in[9];   // (4,64)
    const float* t0_W1   = (const float*)d_in[10];  // (27,64,32)
    const float* t0_bn2  = (const float*)d_in[11];  // (4,32)
    const float* t0_W2   = (const float*)d_in[12];  // (27,32,32)
    const float* t0_Wsc  = (const float*)d_in[13];  // (64,32)
    const float* t1_W    = (const float*)d_in[14];  // (2,27,32,32)
    const float* t1_bn   = (const float*)d_in[15];  // (2,4,32)
    const int* s0i = (const int*)d_in[16];
    const int* s0o = (const int*)d_in[17];
    const int* s1i = (const int*)d_in[18];
    const int* s1o = (const int*)d_in[19];
    const int* dni = (const int*)d_in[20];
    const int* dno = (const int*)d_in[21];
    const int* n1p = (const int*)d_in[22];          // device scalar n1

    const int n0 = in_sizes[0] / 32;
    const int P0 = in_sizes[16] / 27;
    const int P1 = in_sizes[18] / 27;
    const int Pd = in_sizes[20] / 8;

    // ---- workspace layout (all chunks 16B-aligned) ----
    const size_t bufN = (size_t)n0 * 64;
    float* F1 = (float*)d_ws;
    float* F2 = F1 + bufN;
    float* F3 = F2 + bufN;
    float* F4 = F3 + bufN;
    _Float16* Ha = (_Float16*)(F4 + bufN);           // fp16 ping
    _Float16* Hb = Ha + bufN;                        // pong
    int* T0r = (int*)(Hb + bufN);                    // [n0][28]
    int* T1r = T0r + (size_t)n0 * 28;                // [n0][28]
    int* Tdr = T1r + (size_t)n0 * 28;                // [n0][8]
    int* Tur = Tdr + (size_t)n0 * 8;                 // [n0][8]
    _Float16* Wt_res0 = (_Float16*)(Tur + (size_t)n0 * 8);  // 108*1024
    _Float16* Wt_down = Wt_res0 + 108 * 1024;        // 8*2048
    _Float16* Wt_res1 = Wt_down + 8 * 2048;          // 108*4096
    _Float16* Wt_up   = Wt_res1 + (size_t)108 * 4096;// 8*2048
    _Float16* Wt_t01  = Wt_up + 8 * 2048;            // 27*2048
    _Float16* Wt_t02  = Wt_t01 + 27 * 2048;          // 27*1024
    _Float16* Wt_t1   = Wt_t02 + 27 * 1024;          // 54*1024
    _Float16* zrow    = Wt_t1 + 54 * 1024;           // 64 zero halfs

    // ---- gather tables ----
    hipMemsetAsync(T0r, 0xFF, (size_t)n0 * 28 * 4, stream);
    hipMemsetAsync(T1r, 0xFF, (size_t)n0 * 28 * 4, stream);
    hipMemsetAsync(Tdr, 0xFF, (size_t)n0 * 8 * 4, stream);
    hipMemsetAsync(Tur, 0xFF, (size_t)n0 * 8 * 4, stream);
    hipMemsetAsync(zrow, 0, 64 * sizeof(_Float16), stream);
    auto build = [&](const int* pin, const int* pout, int K, int P,
                     int padc, const int* padd, int KPAD, int* T) {
        hipLaunchKernelGGL(build_table_kernel, dim3((K * P + 255) / 256),
                           dim3(256), 0, stream, pin, pout, K, P, padc, padd,
                           KPAD, T);
    };
    build(s0i, s0o, 27, P0, n0, nullptr, 28, T0r);
    build(s1i, s1o, 27, P1, 0, n1p, 28, T1r);
    build(dni, dno, 8, Pd, n0, nullptr, 8, Tdr);
    build(dno, dni, 8, Pd, 0, n1p, 8, Tur);   // up: roles swapped

    // ---- weight convert+transpose ----
    auto wcvt = [&](const float* src, _Float16* dst, int K, int CI, int CO) {
        const int tot = K * CI * CO;
        hipLaunchKernelGGL(wcvt_kernel, dim3((tot + 255) / 256), dim3(256), 0,
                           stream, src, dst, K, CI, CO);
    };
    wcvt(res0_W, Wt_res0, 108, 32, 32);
    wcvt(down_W, Wt_down, 8, 32, 64);
    wcvt(res1_W, Wt_res1, 108, 64, 64);
    wcvt(up_W,   Wt_up,   8, 64, 32);
    wcvt(t0_W1,  Wt_t01, 27, 64, 32);
    wcvt(t0_W2,  Wt_t02, 27, 32, 32);
    wcvt(t1_W,   Wt_t1,  54, 32, 32);

    const int g32 = (n0 * 32 + 255) / 256;
    const int g64 = (n0 * 64 + 255) / 256;
    const int gmc = (n0 + 15) / 16;   // mconv grid (16 rows/block)

    auto mc3232 = [&](const _Float16* xin, const _Float16* Wtp, const int* T,
                      const float* add, float* fo, const float* bn, _Float16* ho,
                      int nc, const int* nd) {
        hipLaunchKernelGGL((mconv_kernel<32, 32, 27, 28>), dim3(gmc), dim3(256),
                           0, stream, xin, Wtp, T, zrow, add, fo, bn, ho, nc, nd);
    };
    auto mc6464 = [&](const _Float16* xin, const _Float16* Wtp,
                      const float* add, float* fo, const float* bn, _Float16* ho) {
        hipLaunchKernelGGL((mconv_kernel<64, 64, 27, 28>), dim3(gmc), dim3(256),
                           0, stream, xin, Wtp, T1r, zrow, add, fo, bn, ho, 0, n1p);
    };

    // 0: first bn_relu (feats -> Ha)
    hipLaunchKernelGGL((bn_relu_kernel<32>), dim3(g32), dim3(256), 0, stream,
                       feats, res0_bn + 0 * 128, Ha, n0, nullptr);
    // 1: res0.0 conv0: Ha -> Hb
    mc3232(Ha, Wt_res0 + 0 * 27 * 1024, T0r, nullptr, nullptr,
           res0_bn + 1 * 128, Hb, n0, nullptr);
    // 2: res0.0 conv1 (+feats): Hb -> F2, Ha
    mc3232(Hb, Wt_res0 + 1 * 27 * 1024, T0r, feats, F2,
           res0_bn + 2 * 128, Ha, n0, nullptr);
    // 3: res0.1 conv0: Ha -> Hb
    mc3232(Ha, Wt_res0 + 2 * 27 * 1024, T0r, nullptr, nullptr,
           res0_bn + 3 * 128, Hb, n0, nullptr);
    // 4: res0.1 conv1 (+F2): Hb -> F3 (identity), Ha [bn=down_bn]
    mc3232(Hb, Wt_res0 + 3 * 27 * 1024, T0r, F2, F3, down_bn, Ha, n0, nullptr);
    // 5: down conv: Ha -> F1 (n1 x 64), Hb [bn=res1_bn 0.0]
    hipLaunchKernelGGL((mconv_kernel<32, 64, 8, 8>), dim3(gmc), dim3(256), 0,
                       stream, Ha, Wt_down, Tdr, zrow, (const float*)nullptr, F1,
                       res1_bn + 0 * 256, Hb, 0, n1p);
    // 6: res1.0 conv0: Hb -> Ha
    mc6464(Hb, Wt_res1 + 0 * 27 * 4096, nullptr, nullptr, res1_bn + 1 * 256, Ha);
    // 7: res1.0 conv1 (+F1): Ha -> F4, Hb
    mc6464(Ha, Wt_res1 + 1 * 27 * 4096, F1, F4, res1_bn + 2 * 256, Hb);
    // 8: res1.1 conv0: Hb -> Ha
    mc6464(Hb, Wt_res1 + 2 * 27 * 4096, nullptr, nullptr, res1_bn + 3 * 256, Ha);
    // 9: res1.1 conv1 (+F4): Ha -> F1, Hb [bn=up_bn]
    mc6464(Ha, Wt_res1 + 3 * 27 * 4096, F4, F1, up_bn, Hb);
    // 10: up conv: Hb(level1) -> F2 (n0 x 32), no hout
    hipLaunchKernelGGL((mconv_kernel<64, 32, 8, 8>), dim3(gmc), dim3(256), 0,
                       stream, Hb, Wt_up, Tur, zrow, (const float*)nullptr, F2,
                       (const float*)nullptr, (_Float16*)nullptr, n0, nullptr);
    // 11: concat+bn: [F3|F2] -> F4 fp32, Ha fp16 [bn=t0_bn1]
    hipLaunchKernelGGL(concat_bn_kernel, dim3(g64), dim3(256), 0, stream,
                       F3, F2, F4, t0_bn1, Ha, n0);
    // 12: tail0 conv1 (64->32): Ha -> Hb [bn=t0_bn2]
    hipLaunchKernelGGL((mconv_kernel<64, 32, 27, 28>), dim3(gmc), dim3(256), 0,
                       stream, Ha, Wt_t01, T0r, zrow, (const float*)nullptr,
                       (float*)nullptr, t0_bn2, Hb, n0, nullptr);
    // 13: shortcut: F2 = F4 @ Wsc
    hipLaunchKernelGGL(dense_mm_kernel, dim3(g32), dim3(256), 0, stream,
                       F4, t0_Wsc, F2, n0);
    // 14: tail0 conv2 (+F2): Hb -> F2, Ha [bn=t1_bn0]  (1:1 in-place safe)
    mc3232(Hb, Wt_t02, T0r, F2, F2, t1_bn + 0 * 128, Ha, n0, nullptr);
    // 15: tail1 conv0: Ha -> Hb
    mc3232(Ha, Wt_t1 + 0 * 27 * 1024, T0r, nullptr, nullptr,
           t1_bn + 1 * 128, Hb, n0, nullptr);
    // 16: tail1 conv1 (+F2): Hb -> d_out
    mc3232(Hb, Wt_t1 + 1 * 27 * 1024, T0r, F2, (float*)d_out,
           nullptr, nullptr, n0, nullptr);
}

// Round 8
// 528.622 us; speedup vs baseline: 7.4953x; 1.2406x over previous
//
#include <hip/hip_runtime.h>

#define EPS_BN 1e-4f

typedef _Float16 f16x8 __attribute__((ext_vector_type(8)));
typedef float f32x4 __attribute__((ext_vector_type(4)));

// ---------------------------------------------------------------------------
// bn_relu -> fp16 (standalone; only for the first layer input)
// ---------------------------------------------------------------------------
template <int C>
__global__ __launch_bounds__(256) void bn_relu_kernel(
    const float* __restrict__ x, const float* __restrict__ bn,
    _Float16* __restrict__ out, int n_const, const int* __restrict__ n_dev)
{
    const int n = n_dev ? *n_dev : n_const;
    const long total = (long)n * C;
    const long i = (long)blockIdx.x * blockDim.x + threadIdx.x;
    if (i >= total) return;
    const int c = (int)(i & (C - 1));
    const float g = bn[c], b = bn[C + c], m = bn[2 * C + c], v = bn[3 * C + c];
    const float val = (x[i] - m) * (g * rsqrtf(v + EPS_BN)) + b;
    out[i] = (_Float16)fmaxf(val, 0.f);
}

// ---------------------------------------------------------------------------
// Build row-major gather table: Trow[pout[k,p]*KPAD + k] = pin[k,p]
// ---------------------------------------------------------------------------
__global__ __launch_bounds__(256) void build_table_kernel(
    const int* __restrict__ pin, const int* __restrict__ pout,
    int K, int P, int pad_const, const int* __restrict__ pad_dev,
    int KPAD, int* __restrict__ T)
{
    const int e = blockIdx.x * 256 + threadIdx.x;
    if (e >= K * P) return;
    const int pad = pad_dev ? *pad_dev : pad_const;
    const int in = pin[e];
    if (in == pad) return;
    const int k = e / P;
    T[(size_t)pout[e] * KPAD + k] = in;
}

// ---------------------------------------------------------------------------
// Weight convert+transpose: src [K][CIN][COUT] fp32 -> dst [K][COUT][CIN] fp16
// ---------------------------------------------------------------------------
__global__ __launch_bounds__(256) void wcvt_kernel(
    const float* __restrict__ src, _Float16* __restrict__ dst,
    int K, int CIN, int COUT)
{
    const int e = blockIdx.x * 256 + threadIdx.x;
    if (e >= K * CIN * COUT) return;
    const int k = e / (CIN * COUT), r = e % (CIN * COUT);
    const int ci = r / COUT, co = r % COUT;
    dst[(size_t)k * CIN * COUT + (size_t)co * CIN + ci] = (_Float16)src[e];
}

// ---------------------------------------------------------------------------
// MFMA gather conv, shared-A formulation.
// Block = 512 thr = 8 waves = WR row-groups x WC cout-groups; tile BM rows.
// Per tap: A-tile (BM x CIN) gathered ONCE into LDS (MFMA-fragment layout,
// XOR-swizzled, double-buffered; issue-early/write-late). Wave (wr,wc)
// computes rows [wr*M_REP*16..) x couts [wc*16..+16); B slices disjoint
// per wc -> block reads exactly one W copy per tap.
//   v = sum_k A @ W[k] (+ add);  fout = v;  hout = bn_relu(v)
// A-frag LDS slot (16B units): a16 = ((m*KK+kk)*64 + lane), swz = a16^((a16>>4)&7)
// C/D: col = lane&15, row = (lane>>4)*4 + reg   [m89]
// ---------------------------------------------------------------------------
template <int CIN, int COUT, int K, int KPAD, int WR, int WC, int M_REP>
__global__ __launch_bounds__(512, 4) void mconv_kernel(
    const _Float16* __restrict__ x, const _Float16* __restrict__ Wt,
    const int* __restrict__ Trow,
    const float* __restrict__ add, float* __restrict__ fout,
    const float* __restrict__ bnx, _Float16* __restrict__ hout,
    int n_const, const int* __restrict__ n_dev)
{
    constexpr int BM = WR * M_REP * 16;
    constexpr int KK = CIN / 32;
    constexpr int SLOTS = BM * CIN / 8;          // 16B slots per tap buffer
    constexpr int SPT = (SLOTS + 511) / 512;     // slots per thread (1 or 2)
    constexpr int SEGS = CIN / 8;                // 16B segs per row
    __shared__ _Float16 A[2][SLOTS * 8];
    __shared__ int TL[BM * K];

    const int n = n_dev ? *n_dev : n_const;
    const int row0 = blockIdx.x * BM;
    if (row0 >= n) return;                       // block-uniform exit

    const int tid = threadIdx.x;
    const int wave = tid >> 6, lane = tid & 63;
    const int lrow = lane & 15, g = lane >> 4;
    const int wr = wave / WC, wc = wave % WC;

    // ---- stage tap-index table (rows beyond n -> -1) ----
    for (int idx = tid; idx < BM * K; idx += 512) {
        const int r = idx / K, k = idx % K;
        TL[idx] = (row0 + r < n) ? Trow[(size_t)(row0 + r) * KPAD + k] : -1;
    }
    __syncthreads();

    auto stage_issue = [&](int k, f16x8 (&v)[SPT]) {
#pragma unroll
        for (int s = 0; s < SPT; ++s) {
            const int slot = tid + s * 512;
            if (slot < SLOTS) {
                const int r = slot / SEGS, seg = slot % SEGS;
                const int t = TL[r * K + k];
                v[s] = (t >= 0) ? *(const f16x8*)(x + (size_t)t * CIN + seg * 8)
                                : (f16x8)(_Float16)0.f;
            }
        }
    };
    auto stage_write = [&](int buf, f16x8 (&v)[SPT]) {
#pragma unroll
        for (int s = 0; s < SPT; ++s) {
            const int slot = tid + s * 512;
            if (slot < SLOTS) {
                const int r = slot / SEGS, seg = slot % SEGS;
                const int a16 = ((r >> 4) * KK + (seg >> 2)) * 64 +
                                (seg & 3) * 16 + (r & 15);
                const int sw = a16 ^ ((a16 >> 4) & 7);
                *(f16x8*)(&A[buf][sw * 8]) = v[s];
            }
        }
    };

    f32x4 acc[M_REP];
#pragma unroll
    for (int m = 0; m < M_REP; ++m) acc[m] = (f32x4)0.f;

    f16x8 st[SPT];
    stage_issue(0, st);
    stage_write(0, st);
    __syncthreads();

    for (int k = 0; k < K; ++k) {
        f16x8 nst[SPT];
        if (k + 1 < K) stage_issue(k + 1, nst);   // loads in flight over MFMAs

        // B frags: disjoint per wc; 16B per lane
        const _Float16* wb = Wt + ((size_t)k * COUT + wc * 16 + lrow) * CIN + g * 8;
        f16x8 b[KK];
#pragma unroll
        for (int kk = 0; kk < KK; ++kk) b[kk] = *(const f16x8*)(wb + kk * 32);

        const _Float16* Ab = A[k & 1];
#pragma unroll
        for (int m = 0; m < M_REP; ++m) {
#pragma unroll
            for (int kk = 0; kk < KK; ++kk) {
                const int a16 = ((wr * M_REP + m) * KK + kk) * 64 + lane;
                const int sw = a16 ^ ((a16 >> 4) & 7);
                const f16x8 av = *(const f16x8*)(&Ab[sw * 8]);
                acc[m] = __builtin_amdgcn_mfma_f32_16x16x32_f16(av, b[kk], acc[m],
                                                                0, 0, 0);
            }
        }

        if (k + 1 < K) stage_write((k + 1) & 1, nst);  // drains vmcnt here
        __syncthreads();
    }

    // ---- epilogue: add, fp32 out, fused bn_relu fp16 out ----
#pragma unroll
    for (int m = 0; m < M_REP; ++m) {
        const int rbase = row0 + (wr * M_REP + m) * 16 + g * 4;
        const int c = wc * 16 + lrow;
        float sc = 0.f, mm = 0.f, be = 0.f;
        if (hout) {
            const float ga = bnx[c], va = bnx[3 * COUT + c];
            be = bnx[COUT + c];
            mm = bnx[2 * COUT + c];
            sc = ga * rsqrtf(va + EPS_BN);
        }
#pragma unroll
        for (int i = 0; i < 4; ++i) {
            const int r = rbase + i;
            if (r < n) {
                const size_t o = (size_t)r * COUT + c;
                float v = acc[m][i];
                if (add) v += add[o];
                if (fout) fout[o] = v;
                if (hout) hout[o] = (_Float16)fmaxf((v - mm) * sc + be, 0.f);
            }
        }
    }
}

// ---------------------------------------------------------------------------
// concat + fused bn_relu: fout[i] = concat(a,b); hout[i] = bn_relu(fout[i])
// ---------------------------------------------------------------------------
__global__ __launch_bounds__(256) void concat_bn_kernel(
    const float* __restrict__ a, const float* __restrict__ b,
    float* __restrict__ fout, const float* __restrict__ bnx,
    _Float16* __restrict__ hout, int n)
{
    const int i = blockIdx.x * 256 + threadIdx.x;
    if (i >= n * 64) return;
    const int row = i >> 6, c = i & 63;
    const float v = (c < 32) ? a[row * 32 + c] : b[row * 32 + (c - 32)];
    fout[i] = v;
    const float g = bnx[c], be = bnx[64 + c], m = bnx[128 + c], va = bnx[192 + c];
    hout[i] = (_Float16)fmaxf((v - m) * (g * rsqrtf(va + EPS_BN)) + be, 0.f);
}

// ---------------------------------------------------------------------------
// dense matmul: out[n x 32] = x[n x 64] @ W[64 x 32]   (fp32 scalar)
// ---------------------------------------------------------------------------
__global__ __launch_bounds__(256) void dense_mm_kernel(
    const float* __restrict__ x, const float* __restrict__ W,
    float* __restrict__ out, int n)
{
    __shared__ float Wl[64 * 32];
    for (int i = threadIdx.x; i < 64 * 32; i += 256) Wl[i] = W[i];
    __syncthreads();
    const int idx = blockIdx.x * 256 + threadIdx.x;
    const int row = idx >> 5, c = idx & 31;
    if (row >= n) return;
    const float* xr = x + (size_t)row * 64;
    float acc = 0.f;
#pragma unroll
    for (int q = 0; q < 16; ++q) {
        const float4 xv = *(const float4*)(xr + 4 * q);
        acc = fmaf(xv.x, Wl[(4 * q + 0) * 32 + c], acc);
        acc = fmaf(xv.y, Wl[(4 * q + 1) * 32 + c], acc);
        acc = fmaf(xv.z, Wl[(4 * q + 2) * 32 + c], acc);
        acc = fmaf(xv.w, Wl[(4 * q + 3) * 32 + c], acc);
    }
    out[(size_t)row * 32 + c] = acc;
}

// ---------------------------------------------------------------------------

extern "C" void kernel_launch(void* const* d_in, const int* in_sizes, int n_in,
                              void* d_out, int out_size, void* d_ws, size_t ws_size,
                              hipStream_t stream)
{
    const float* feats   = (const float*)d_in[0];
    const float* res0_W  = (const float*)d_in[1];   // (2,2,27,32,32)
    const float* res0_bn = (const float*)d_in[2];   // (2,2,4,32)
    const float* down_bn = (const float*)d_in[3];   // (4,32)
    const float* down_W  = (const float*)d_in[4];   // (8,32,64)
    const float* res1_W  = (const float*)d_in[5];   // (2,2,27,64,64)
    const float* res1_bn = (const float*)d_in[6];   // (2,2,4,64)
    const float* up_bn   = (const float*)d_in[7];   // (4,64)
    const float* up_W    = (const float*)d_in[8];   // (8,64,32)
    const float* t0_bn1  = (const float*)d_in[9];   // (4,64)
    const float* t0_W1   = (const float*)d_in[10];  // (27,64,32)
    const float* t0_bn2  = (const float*)d_in[11];  // (4,32)
    const float* t0_W2   = (const float*)d_in[12];  // (27,32,32)
    const float* t0_Wsc  = (const float*)d_in[13];  // (64,32)
    const float* t1_W    = (const float*)d_in[14];  // (2,27,32,32)
    const float* t1_bn   = (const float*)d_in[15];  // (2,4,32)
    const int* s0i = (const int*)d_in[16];
    const int* s0o = (const int*)d_in[17];
    const int* s1i = (const int*)d_in[18];
    const int* s1o = (const int*)d_in[19];
    const int* dni = (const int*)d_in[20];
    const int* dno = (const int*)d_in[21];
    const int* n1p = (const int*)d_in[22];          // device scalar n1

    const int n0 = in_sizes[0] / 32;
    const int P0 = in_sizes[16] / 27;
    const int P1 = in_sizes[18] / 27;
    const int Pd = in_sizes[20] / 8;

    // ---- workspace layout (all chunks 16B-aligned) ----
    const size_t bufN = (size_t)n0 * 64;
    float* F1 = (float*)d_ws;
    float* F2 = F1 + bufN;
    float* F3 = F2 + bufN;
    float* F4 = F3 + bufN;
    _Float16* Ha = (_Float16*)(F4 + bufN);           // fp16 ping
    _Float16* Hb = Ha + bufN;                        // pong
    int* T0r = (int*)(Hb + bufN);                    // [n0][28]
    int* T1r = T0r + (size_t)n0 * 28;                // [n0][28]
    int* Tdr = T1r + (size_t)n0 * 28;                // [n0][8]
    int* Tur = Tdr + (size_t)n0 * 8;                 // [n0][8]
    _Float16* Wt_res0 = (_Float16*)(Tur + (size_t)n0 * 8);  // 108*1024
    _Float16* Wt_down = Wt_res0 + 108 * 1024;        // 8*2048
    _Float16* Wt_res1 = Wt_down + 8 * 2048;          // 108*4096
    _Float16* Wt_up   = Wt_res1 + (size_t)108 * 4096;// 8*2048
    _Float16* Wt_t01  = Wt_up + 8 * 2048;            // 27*2048
    _Float16* Wt_t02  = Wt_t01 + 27 * 2048;          // 27*1024
    _Float16* Wt_t1   = Wt_t02 + 27 * 1024;          // 54*1024

    // ---- gather tables ----
    hipMemsetAsync(T0r, 0xFF, (size_t)n0 * 28 * 4, stream);
    hipMemsetAsync(T1r, 0xFF, (size_t)n0 * 28 * 4, stream);
    hipMemsetAsync(Tdr, 0xFF, (size_t)n0 * 8 * 4, stream);
    hipMemsetAsync(Tur, 0xFF, (size_t)n0 * 8 * 4, stream);
    auto build = [&](const int* pin, const int* pout, int K, int P,
                     int padc, const int* padd, int KPAD, int* T) {
        hipLaunchKernelGGL(build_table_kernel, dim3((K * P + 255) / 256),
                           dim3(256), 0, stream, pin, pout, K, P, padc, padd,
                           KPAD, T);
    };
    build(s0i, s0o, 27, P0, n0, nullptr, 28, T0r);
    build(s1i, s1o, 27, P1, 0, n1p, 28, T1r);
    build(dni, dno, 8, Pd, n0, nullptr, 8, Tdr);
    build(dno, dni, 8, Pd, 0, n1p, 8, Tur);   // up: roles swapped

    // ---- weight convert+transpose ----
    auto wcvt = [&](const float* src, _Float16* dst, int K, int CI, int CO) {
        const int tot = K * CI * CO;
        hipLaunchKernelGGL(wcvt_kernel, dim3((tot + 255) / 256), dim3(256), 0,
                           stream, src, dst, K, CI, CO);
    };
    wcvt(res0_W, Wt_res0, 108, 32, 32);
    wcvt(down_W, Wt_down, 8, 32, 64);
    wcvt(res1_W, Wt_res1, 108, 64, 64);
    wcvt(up_W,   Wt_up,   8, 64, 32);
    wcvt(t0_W1,  Wt_t01, 27, 64, 32);
    wcvt(t0_W2,  Wt_t02, 27, 32, 32);
    wcvt(t1_W,   Wt_t1,  54, 32, 32);

    const int g32 = (n0 * 32 + 255) / 256;
    const int g64 = (n0 * 64 + 255) / 256;
    const int gm128 = (n0 + 127) / 128;   // BM=128 grids
    const int gm64  = (n0 + 63) / 64;     // BM=64 grids

    // 32->32, K=27: WR=4, WC=2, BM=128
    auto mc3232 = [&](const _Float16* xin, const _Float16* Wtp, const int* T,
                      const float* add, float* fo, const float* bn, _Float16* ho,
                      int nc, const int* nd) {
        hipLaunchKernelGGL((mconv_kernel<32, 32, 27, 28, 4, 2, 2>), dim3(gm128),
                           dim3(512), 0, stream, xin, Wtp, T, add, fo, bn, ho,
                           nc, nd);
    };
    // 64->64, K=27: WR=2, WC=4, BM=64
    auto mc6464 = [&](const _Float16* xin, const _Float16* Wtp,
                      const float* add, float* fo, const float* bn, _Float16* ho) {
        hipLaunchKernelGGL((mconv_kernel<64, 64, 27, 28, 2, 4, 2>), dim3(gm64),
                           dim3(512), 0, stream, xin, Wtp, T1r, add, fo, bn, ho,
                           0, n1p);
    };

    // 0: first bn_relu (feats -> Ha)
    hipLaunchKernelGGL((bn_relu_kernel<32>), dim3(g32), dim3(256), 0, stream,
                       feats, res0_bn + 0 * 128, Ha, n0, nullptr);
    // 1: res0.0 conv0: Ha -> Hb
    mc3232(Ha, Wt_res0 + 0 * 27 * 1024, T0r, nullptr, nullptr,
           res0_bn + 1 * 128, Hb, n0, nullptr);
    // 2: res0.0 conv1 (+feats): Hb -> F2, Ha
    mc3232(Hb, Wt_res0 + 1 * 27 * 1024, T0r, feats, F2,
           res0_bn + 2 * 128, Ha, n0, nullptr);
    // 3: res0.1 conv0: Ha -> Hb
    mc3232(Ha, Wt_res0 + 2 * 27 * 1024, T0r, nullptr, nullptr,
           res0_bn + 3 * 128, Hb, n0, nullptr);
    // 4: res0.1 conv1 (+F2): Hb -> F3 (identity), Ha [bn=down_bn]
    mc3232(Hb, Wt_res0 + 3 * 27 * 1024, T0r, F2, F3, down_bn, Ha, n0, nullptr);
    // 5: down conv (32->64, K=8): Ha -> F1 (n1 x 64), Hb [bn=res1_bn 0.0]
    hipLaunchKernelGGL((mconv_kernel<32, 64, 8, 8, 2, 4, 2>), dim3(gm64),
                       dim3(512), 0, stream, Ha, Wt_down, Tdr,
                       (const float*)nullptr, F1, res1_bn + 0 * 256, Hb, 0, n1p);
    // 6: res1.0 conv0: Hb -> Ha
    mc6464(Hb, Wt_res1 + 0 * 27 * 4096, nullptr, nullptr, res1_bn + 1 * 256, Ha);
    // 7: res1.0 conv1 (+F1): Ha -> F4, Hb
    mc6464(Ha, Wt_res1 + 1 * 27 * 4096, F1, F4, res1_bn + 2 * 256, Hb);
    // 8: res1.1 conv0: Hb -> Ha
    mc6464(Hb, Wt_res1 + 2 * 27 * 4096, nullptr, nullptr, res1_bn + 3 * 256, Ha);
    // 9: res1.1 conv1 (+F4): Ha -> F1, Hb [bn=up_bn]
    mc6464(Ha, Wt_res1 + 3 * 27 * 4096, F4, F1, up_bn, Hb);
    // 10: up conv (64->32, K=8): Hb(level1) -> F2 (n0 x 32), no hout
    hipLaunchKernelGGL((mconv_kernel<64, 32, 8, 8, 4, 2, 2>), dim3(gm128),
                       dim3(512), 0, stream, Hb, Wt_up, Tur,
                       (const float*)nullptr, F2, (const float*)nullptr,
                       (_Float16*)nullptr, n0, nullptr);
    // 11: concat+bn: [F3|F2] -> F4 fp32, Ha fp16 [bn=t0_bn1]
    hipLaunchKernelGGL(concat_bn_kernel, dim3(g64), dim3(256), 0, stream,
                       F3, F2, F4, t0_bn1, Ha, n0);
    // 12: tail0 conv1 (64->32, K=27): Ha -> Hb [bn=t0_bn2]
    hipLaunchKernelGGL((mconv_kernel<64, 32, 27, 28, 4, 2, 2>), dim3(gm128),
                       dim3(512), 0, stream, Ha, Wt_t01, T0r,
                       (const float*)nullptr, (float*)nullptr, t0_bn2, Hb,
                       n0, nullptr);
    // 13: shortcut: F2 = F4 @ Wsc
    hipLaunchKernelGGL(dense_mm_kernel, dim3(g32), dim3(256), 0, stream,
                       F4, t0_Wsc, F2, n0);
    // 14: tail0 conv2 (+F2): Hb -> F2, Ha [bn=t1_bn0]  (1:1 in-place safe)
    mc3232(Hb, Wt_t02, T0r, F2, F2, t1_bn + 0 * 128, Ha, n0, nullptr);
    // 15: tail1 conv0: Ha -> Hb
    mc3232(Ha, Wt_t1 + 0 * 27 * 1024, T0r, nullptr, nullptr,
           t1_bn + 1 * 128, Hb, n0, nullptr);
    // 16: tail1 conv1 (+F2): Hb -> d_out
    mc3232(Hb, Wt_t1 + 1 * 27 * 1024, T0r, F2, (float*)d_out,
           nullptr, nullptr, n0, nullptr);
}